// Round 10
// baseline (1557.512 us; speedup 1.0000x reference)
//
#include <hip/hip_runtime.h>

typedef unsigned short u16;
typedef short s16x8 __attribute__((ext_vector_type(8)));   // 8 bf16 bit-patterns
typedef float f32x4 __attribute__((ext_vector_type(4)));

#define DI __device__ __forceinline__

constexpr int N_ = 50000;
constexpr int E_ = 400000;
constexpr int G_ = 64;

DI u16 f2bf(float f) {
    union { unsigned u; float f; } c; c.f = f;
    unsigned u = c.u;
    u += 0x7fffu + ((u >> 16) & 1u);   // RNE
    return (u16)(u >> 16);
}

DI s16x8 ldv(const u16* p) { return *(const s16x8*)p; }
DI f32x4 MFMA(s16x8 a, s16x8 b, f32x4 c) {
    return __builtin_amdgcn_mfma_f32_16x16x32_bf16(a, b, c, 0, 0, 0);
}

// ---------------------------------------------------------------------------
// Named kernel (symbol required by harness): zero agg0+agg1 (40 MB) and
// repack weights f32 -> bf16 in MFMA-FRAGMENT-ORDER TILES, folding
//   [xi, xj-xi] @ W = xi @ (W_a - W_b) + xj @ W_b.
// Tile layout (W1/W2): section = 512 elems = 1 KB = B-fragment for one
// (n-half, k-chunk), elem(col,kq,j) at col*32 + kq*8 + j.
// Section id = n0c*(2*KA) + s*2 + b01.  W3: section id = ch*7 + u,
// elem(col,kq,j): n3 = u*16+col, k = ch*32+kq*8+j.
// ---------------------------------------------------------------------------
__global__ __launch_bounds__(256)
void ModelGNN_35304631174019_kernel(
          const float* __restrict__ l0w1, const float* __restrict__ l0w2,
          const float* __restrict__ l0w3, const float* __restrict__ l1w1,
          const float* __restrict__ l1w2, const float* __restrict__ l1w3,
          float4* __restrict__ aggz,
          u16* __restrict__ wt0, u16* __restrict__ wt1,
          u16* __restrict__ wt2a, u16* __restrict__ wt2b,
          u16* __restrict__ wt3a, u16* __restrict__ wt3b)
{
    int i = blockIdx.x * 256 + threadIdx.x;
    if (i < 2500000) { aggz[i] = make_float4(0.f, 0.f, 0.f, 0.f); return; }  // agg0+agg1
    int f = i - 2500000;

    if (f < 10240) {                       // wt0: layer0 W1, KP=32 (KA=1)
        int sec = f >> 9, w = f & 511;
        int col = w >> 5, rem = w & 31;
        int n0c = sec >> 1, b01 = sec & 1;
        int n = n0c * 32 + b01 * 16 + col, k = rem;
        u16 v = 0;
        if (n < 300) {
            if (k < 7) v = f2bf(l0w1[k * 300 + n] - l0w1[(7 + k) * 300 + n]);
            else if (k >= 16 && k < 23) v = f2bf(l0w1[(7 + (k - 16)) * 300 + n]);
        }
        wt0[f] = v; return;
    }
    f -= 10240;
    if (f < 71680) {                       // wt1: layer1 W1, KP=224 (KA=7)
        int sec = f >> 9, w = f & 511;
        int col = w >> 5, rem = w & 31;
        int n0c = sec / 14, r = sec % 14;
        int s = r >> 1, b01 = r & 1;
        int n = n0c * 32 + b01 * 16 + col, k = s * 32 + rem;
        u16 v = 0;
        if (n < 300) {
            if (k < 100) v = f2bf(l1w1[k * 300 + n] - l1w1[(100 + k) * 300 + n]);
            else if (k >= 112 && k < 212) v = f2bf(l1w1[(100 + (k - 112)) * 300 + n]);
        }
        wt1[f] = v; return;
    }
    f -= 71680;
    if (f < 204800) {                      // wt2a / wt2b: 300x300, K=320 (KA=10)
        const float* src = (f < 102400) ? l0w2 : l1w2;
        u16* dst = (f < 102400) ? wt2a : wt2b;
        int f2 = (f < 102400) ? f : f - 102400;
        int sec = f2 >> 9, w = f2 & 511;
        int col = w >> 5, rem = w & 31;
        int n0c = sec / 20, r = sec % 20;
        int s = r >> 1, b01 = r & 1;
        int n = n0c * 32 + b01 * 16 + col, k = s * 32 + rem;
        dst[f2] = (n < 300 && k < 300) ? f2bf(src[k * 300 + n]) : (u16)0;
        return;
    }
    f -= 204800;
    if (f < 71680) {                       // wt3a / wt3b: 300x100 -> [112 n3][320 k]
        const float* src = (f < 35840) ? l0w3 : l1w3;
        u16* dst = (f < 35840) ? wt3a : wt3b;
        int f2 = (f < 35840) ? f : f - 35840;
        int sec = f2 >> 9, w = f2 & 511;
        int col = w >> 5, rem = w & 31;
        int ch = sec / 7, u = sec % 7;
        int n3 = u * 16 + col, k = ch * 32 + rem;
        dst[f2] = (n3 < 100 && k < 300) ? f2bf(src[k * 100 + n3]) : (u16)0;
        return;
    }
}

// ---------------------------------------------------------------------------
// edge_mlp: fused per-edge 3-layer MLP + clamped scatter-max via MFMA.
// One wave = 16 edges; wave-private LDS; no barriers. Weights are in
// fragment-order tiles: every B-load is a contiguous 1 KB wave-load.
// R10 change: ALL weight loads of a chunk are batched into register arrays
// BEFORE any MFMA consumes them (bb[2KA] / bb[20]+b3[7]), and
// __launch_bounds__(256,2) lifts the VGPR cap so ~27 loads stay in flight
// (R9's VGPR_Count=68 capped MLP at ~4 loads -> serial L2 latency).
// Layouts (m89/m120): A: m=lane&15,k=quad*8+j ; B: n=lane&15,k=quad*8+j ;
// C/D: col=lane&15, row=quad*4+reg.
// relu(where(cnt>0,segmax,0)) == int atomicMax of relu'd msgs into 0-init buf.
// ---------------------------------------------------------------------------
template<bool FIRST>
__global__ __launch_bounds__(256, 2)
void edge_mlp(const float* __restrict__ X, const float* __restrict__ H0,
              const int* __restrict__ ei,
              const u16* __restrict__ W1, const float* __restrict__ B1,
              const u16* __restrict__ W2, const float* __restrict__ B2,
              const u16* __restrict__ W3, const float* __restrict__ B3,
              float* __restrict__ agg)
{
    constexpr int KP = FIRST ? 32 : 224;
    constexpr int KA = KP / 32;
    __shared__ __align__(16) u16 H1s[4 * 16 * 328];   // 41,984 B (wave-private slices)
    __shared__ __align__(16) u16 SCR[4 * 16 * 40];    //  5,120 B (wave-private slices)

    const int tid  = threadIdx.x;
    const int wave = tid >> 6, lane = tid & 63;
    const int col  = lane & 15, kq = lane >> 4;
    const int ebase = blockIdx.x * 64 + wave * 16;
    const int fragoff = col * 32 + kq * 8;            // in-section lane offset

    u16* H1w = H1s + wave * (16 * 328);
    u16* SCw = SCR + wave * (16 * 40);

    s16x8 aF[KA];
    if constexpr (FIRST) {
        // gather [xi | xj] into SCw as bf16 IN[16][40] (K padded to 32)
        for (int s = lane; s < 16 * 32; s += 64) {
            int e = s >> 5, k = s & 31;
            u16 v = 0;
            if (k < 7)                  v = f2bf(X[(size_t)ei[E_ + ebase + e] * 7 + k]);
            else if (k >= 16 && k < 23) v = f2bf(X[(size_t)ei[ebase + e] * 7 + (k - 16)]);
            SCw[e * 40 + k] = v;
        }
        #pragma unroll
        for (int s = 0; s < KA; ++s) aF[s] = ldv(SCw + col * 40 + s * 32 + kq * 8);
    } else {
        // build A-fragments from global agg0 (h0, f32 -> bf16); batch the
        // raw gather loads first, then convert.
        const int dn = ei[E_ + ebase + col];   // dst node (x_i) of this lane's edge
        const int sn = ei[ebase + col];        // src node (x_j)
        float4 raw[2 * KA][2];
        #pragma unroll
        for (int s = 0; s < KA; ++s) {
            int b = s * 4 + kq;                // 8-elem k-group, 0..27; k = 8b+j
            int node = (b < 14) ? dn : sn;
            int c = ((b < 14) ? b : b - 14) * 8;
            const float* r = H0 + (size_t)node * 100 + c;
            if (c < 104) raw[s][0] = *(const float4*)r;
            if (c < 96)  raw[s][1] = *(const float4*)(r + 4);
        }
        #pragma unroll
        for (int s = 0; s < KA; ++s) {
            int b = s * 4 + kq;
            int c = ((b < 14) ? b : b - 14) * 8;
            s16x8 t = {0, 0, 0, 0, 0, 0, 0, 0};
            if (c < 104) {
                float4 lo = raw[s][0];
                t[0] = (short)f2bf(lo.x); t[1] = (short)f2bf(lo.y);
                t[2] = (short)f2bf(lo.z); t[3] = (short)f2bf(lo.w);
                if (c < 96) {
                    float4 hi = raw[s][1];
                    t[4] = (short)f2bf(hi.x); t[5] = (short)f2bf(hi.y);
                    t[6] = (short)f2bf(hi.z); t[7] = (short)f2bf(hi.w);
                }
            }
            aF[s] = t;
        }
    }

    // GEMM1: [16,KP] x Wt1 -> H1[16][320] (relu, bf16). Loads batched.
    #pragma unroll 1
    for (int t2 = 0; t2 < 10; ++t2) {
        const int n0 = t2 * 32;
        const u16* w0 = W1 + (size_t)(t2 * 2 * KA) * 512 + fragoff;
        s16x8 bb[2 * KA];
        #pragma unroll
        for (int q = 0; q < 2 * KA; ++q) bb[q] = ldv(w0 + q * 512);
        f32x4 z = {0.f, 0.f, 0.f, 0.f};
        f32x4 ac0 = z, ac1 = z;
        #pragma unroll
        for (int s = 0; s < KA; ++s) {
            ac0 = MFMA(aF[s], bb[2 * s],     ac0);
            ac1 = MFMA(aF[s], bb[2 * s + 1], ac1);
        }
        const int n = n0 + col;
        const float bi0 = (n < 300)      ? B1[n]      : 0.f;
        const float bi1 = (n + 16 < 300) ? B1[n + 16] : 0.f;
        #pragma unroll
        for (int r = 0; r < 4; ++r) {
            int row = kq * 4 + r;
            H1w[row * 328 + n]      = f2bf(fmaxf(ac0[r] + bi0, 0.f));
            H1w[row * 328 + n + 16] = f2bf(fmaxf(ac1[r] + bi1, 0.f));
        }
    }

    // A-fragments for GEMM2: this wave's full [16 x 320] from H1 (40 VGPRs)
    s16x8 a2[10];
    #pragma unroll
    for (int s = 0; s < 10; ++s) a2[s] = ldv(H1w + col * 328 + s * 32 + kq * 8);

    f32x4 mac[7];
    #pragma unroll
    for (int u = 0; u < 7; ++u) { f32x4 z = {0.f, 0.f, 0.f, 0.f}; mac[u] = z; }

    // GEMM2 (K=320) fused with GEMM3 in 32-wide chunks of H2.
    // All 27 chunk loads (20 W2-frags + 7 W3-frags) batched up front.
    #pragma unroll 1
    for (int ch = 0; ch < 10; ++ch) {
        const int n0 = ch * 32;
        const u16* w0 = W2 + (size_t)(ch * 20) * 512 + fragoff;
        s16x8 bb[20];
        #pragma unroll
        for (int q = 0; q < 20; ++q) bb[q] = ldv(w0 + q * 512);
        s16x8 b3[7];
        #pragma unroll
        for (int u = 0; u < 7; ++u) b3[u] = ldv(W3 + (size_t)(ch * 7 + u) * 512 + fragoff);
        f32x4 z = {0.f, 0.f, 0.f, 0.f};
        f32x4 ac0 = z, ac1 = z;
        #pragma unroll
        for (int s = 0; s < 10; ++s) {
            ac0 = MFMA(a2[s], bb[2 * s],     ac0);
            ac1 = MFMA(a2[s], bb[2 * s + 1], ac1);
        }
        const int n = n0 + col;
        const float bi0 = (n < 300)      ? B2[n]      : 0.f;
        const float bi1 = (n + 16 < 300) ? B2[n + 16] : 0.f;
        #pragma unroll
        for (int r = 0; r < 4; ++r) {
            int row = kq * 4 + r;
            SCw[row * 40 + col]      = f2bf(fmaxf(ac0[r] + bi0, 0.f));
            SCw[row * 40 + col + 16] = f2bf(fmaxf(ac1[r] + bi1, 0.f));
        }
        // wave-private SCw: lgkmcnt ordering only, no barrier
        s16x8 a3 = ldv(SCw + col * 40 + kq * 8);
        #pragma unroll
        for (int u = 0; u < 7; ++u) mac[u] = MFMA(a3, b3[u], mac[u]);
    }

    // scatter-max: per (u,r) instruction lanes cover 16 consecutive channels
    // x 4 edges -> coalesced atomic sectors. Msgs clamped >=0 (see header).
    const int e0 = ebase + kq * 4;
    int dsts[4];
    #pragma unroll
    for (int r = 0; r < 4; ++r) dsts[r] = ei[E_ + e0 + r];
    #pragma unroll
    for (int u = 0; u < 7; ++u) {
        int c3 = u * 16 + col;
        if (c3 < 100) {
            float bi = B3[c3];
            #pragma unroll
            for (int r = 0; r < 4; ++r) {
                float v = fmaxf(mac[u][r] + bi, 0.f);
                atomicMax((int*)(agg + (size_t)dsts[r] * 100 + c3), __float_as_int(v));
            }
        }
    }
}

// ---------------------------------------------------------------------------
// pool: one block per graph (batch sorted -> binary-search bounds).
// pooled[g] = [addp(100) | meanp(100) | maxp(100) | u(2)]
// ---------------------------------------------------------------------------
__global__ __launch_bounds__(256)
void pool(const float* __restrict__ agg1, const int* __restrict__ batch,
          const float* __restrict__ u, float* __restrict__ pooled)
{
    const int g = blockIdx.x;
    int lo = 0, hi = N_;
    while (lo < hi) { int mid = (lo + hi) >> 1; if (batch[mid] < g) lo = mid + 1; else hi = mid; }
    const int start = lo;
    int lo2 = start, hi2 = N_;
    while (lo2 < hi2) { int mid = (lo2 + hi2) >> 1; if (batch[mid] < g + 1) lo2 = mid + 1; else hi2 = mid; }
    const int end = lo2;

    const int c = threadIdx.x & 127, half = threadIdx.x >> 7;
    float sm = 0.f, mx = 0.f;
    if (c < 100)
        for (int n = start + half; n < end; n += 2) {
            float v = agg1[(size_t)n * 100 + c];
            sm += v; mx = fmaxf(mx, v);
        }
    __shared__ float ssum[128], smax[128];
    if (half) { ssum[c] = sm; smax[c] = mx; }
    __syncthreads();
    if (!half && c < 100) {
        sm += ssum[c]; mx = fmaxf(mx, smax[c]);
        int cnt = end - start;
        pooled[g * 302 + c]       = sm;
        pooled[g * 302 + 100 + c] = sm / fmaxf((float)cnt, 1.f);
        pooled[g * 302 + 200 + c] = mx;   // h>=0 so zero-init max == where(cnt>0,.)
    }
    if (threadIdx.x == 0) {
        pooled[g * 302 + 300] = u[g * 2];
        pooled[g * 302 + 301] = u[g * 2 + 1];
    }
}

// ---------------------------------------------------------------------------
// final 302 -> 100 -> 100 -> 2 MLP, one block per graph, fp32
// ---------------------------------------------------------------------------
__global__ __launch_bounds__(128)
void final_mlp(const float* __restrict__ pooled,
               const float* __restrict__ w1, const float* __restrict__ b1,
               const float* __restrict__ w2, const float* __restrict__ b2,
               const float* __restrict__ w3, const float* __restrict__ b3,
               float* __restrict__ out)
{
    const int g = blockIdx.x, t = threadIdx.x;
    __shared__ float P[302], T1[100], T2[100];
    for (int i = t; i < 302; i += 128) P[i] = pooled[g * 302 + i];
    __syncthreads();
    if (t < 100) {
        float a = b1[t];
        for (int i = 0; i < 302; ++i) a = fmaf(P[i], w1[i * 100 + t], a);
        T1[t] = fmaxf(a, 0.f);
    }
    __syncthreads();
    if (t < 100) {
        float a = b2[t];
        for (int i = 0; i < 100; ++i) a = fmaf(T1[i], w2[i * 100 + t], a);
        T2[t] = fmaxf(a, 0.f);
    }
    __syncthreads();
    if (t < 2) {
        float a = b3[t];
        for (int i = 0; i < 100; ++i) a = fmaf(T2[i], w3[i * 2 + t], a);
        out[g * 2 + t] = a;
    }
}

// ---------------------------------------------------------------------------
extern "C" void kernel_launch(void* const* d_in, const int* in_sizes, int n_in,
                              void* d_out, int out_size, void* d_ws, size_t ws_size,
                              hipStream_t stream)
{
    const float* x     = (const float*)d_in[0];
    const int*   ei    = (const int*)d_in[1];
    const int*   batch = (const int*)d_in[2];
    const float* uu    = (const float*)d_in[3];
    const float *l0w1 = (const float*)d_in[4],  *l0b1 = (const float*)d_in[5];
    const float *l0w2 = (const float*)d_in[6],  *l0b2 = (const float*)d_in[7];
    const float *l0w3 = (const float*)d_in[8],  *l0b3 = (const float*)d_in[9];
    const float *l1w1 = (const float*)d_in[10], *l1b1 = (const float*)d_in[11];
    const float *l1w2 = (const float*)d_in[12], *l1b2 = (const float*)d_in[13];
    const float *l1w3 = (const float*)d_in[14], *l1b3 = (const float*)d_in[15];
    const float *lw1  = (const float*)d_in[16], *lb1  = (const float*)d_in[17];
    const float *lw2  = (const float*)d_in[18], *lb2  = (const float*)d_in[19];
    const float *lw3  = (const float*)d_in[20], *lb3  = (const float*)d_in[21];

    char* w = (char*)d_ws;
    float* agg0   = (float*)(w);                    // 20,000,000 B
    float* agg1   = (float*)(w + 20000000);         // 20,000,000 B
    float* pooled = (float*)(w + 40000000);         //     77,312 B
    u16* wt0  = (u16*)(w + 40077312);               //     20,480 B
    u16* wt1  = (u16*)(w + 40097792);               //    143,360 B
    u16* wt2a = (u16*)(w + 40241152);               //    204,800 B
    u16* wt2b = (u16*)(w + 40445952);               //    204,800 B
    u16* wt3a = (u16*)(w + 40650752);               //     71,680 B
    u16* wt3b = (u16*)(w + 40722432);               //     71,680 B  (total ~38.9 MiB)

    ModelGNN_35304631174019_kernel<<<11166, 256, 0, stream>>>(
        l0w1, l0w2, l0w3, l1w1, l1w2, l1w3,
        (float4*)d_ws, wt0, wt1, wt2a, wt2b, wt3a, wt3b);
    edge_mlp<true ><<<6250, 256, 0, stream>>>(x, nullptr, ei, wt0, l0b1, wt2a, l0b2, wt3a, l0b3, agg0);
    edge_mlp<false><<<6250, 256, 0, stream>>>(nullptr, agg0, ei, wt1, l1b1, wt2b, l1b2, wt3b, l1b3, agg1);
    pool<<<G_, 256, 0, stream>>>(agg1, batch, uu, pooled);
    final_mlp<<<G_, 128, 0, stream>>>(pooled, lw1, lb1, lw2, lb2, lw3, lb3, (float*)d_out);
}

// Round 11
// 1418.173 us; speedup vs baseline: 1.0983x; 1.0983x over previous
//
#include <hip/hip_runtime.h>

typedef unsigned short u16;
typedef short s16x8 __attribute__((ext_vector_type(8)));   // 8 bf16 bit-patterns
typedef float f32x4 __attribute__((ext_vector_type(4)));

#define DI __device__ __forceinline__

constexpr int N_ = 50000;
constexpr int E_ = 400000;
constexpr int G_ = 64;

DI u16 f2bf(float f) {
    union { unsigned u; float f; } c; c.f = f;
    unsigned u = c.u;
    u += 0x7fffu + ((u >> 16) & 1u);   // RNE
    return (u16)(u >> 16);
}

DI s16x8 ldv(const u16* p) { return *(const s16x8*)p; }
DI f32x4 MFMA(s16x8 a, s16x8 b, f32x4 c) {
    return __builtin_amdgcn_mfma_f32_16x16x32_bf16(a, b, c, 0, 0, 0);
}

// ---------------------------------------------------------------------------
// Named kernel (symbol required by harness): zero agg0+agg1 (40 MB) and
// repack weights f32 -> bf16 in MFMA-FRAGMENT-ORDER TILES, folding
//   [xi, xj-xi] @ W = xi @ (W_a - W_b) + xj @ W_b.
// Tile layout (W1/W2): section = 512 elems = 1 KB = B-fragment for one
// (n-half, k-chunk), elem(col,kq,j) at col*32 + kq*8 + j.
// Section id = n0c*(2*KA) + s*2 + b01.  W3: section id = ch*7 + u,
// elem(col,kq,j): n3 = u*16+col, k = ch*32+kq*8+j.
// ---------------------------------------------------------------------------
__global__ __launch_bounds__(256)
void ModelGNN_35304631174019_kernel(
          const float* __restrict__ l0w1, const float* __restrict__ l0w2,
          const float* __restrict__ l0w3, const float* __restrict__ l1w1,
          const float* __restrict__ l1w2, const float* __restrict__ l1w3,
          float4* __restrict__ aggz,
          u16* __restrict__ wt0, u16* __restrict__ wt1,
          u16* __restrict__ wt2a, u16* __restrict__ wt2b,
          u16* __restrict__ wt3a, u16* __restrict__ wt3b)
{
    int i = blockIdx.x * 256 + threadIdx.x;
    if (i < 2500000) { aggz[i] = make_float4(0.f, 0.f, 0.f, 0.f); return; }  // agg0+agg1
    int f = i - 2500000;

    if (f < 10240) {                       // wt0: layer0 W1, KP=32 (KA=1)
        int sec = f >> 9, w = f & 511;
        int col = w >> 5, rem = w & 31;
        int n0c = sec >> 1, b01 = sec & 1;
        int n = n0c * 32 + b01 * 16 + col, k = rem;
        u16 v = 0;
        if (n < 300) {
            if (k < 7) v = f2bf(l0w1[k * 300 + n] - l0w1[(7 + k) * 300 + n]);
            else if (k >= 16 && k < 23) v = f2bf(l0w1[(7 + (k - 16)) * 300 + n]);
        }
        wt0[f] = v; return;
    }
    f -= 10240;
    if (f < 71680) {                       // wt1: layer1 W1, KP=224 (KA=7)
        int sec = f >> 9, w = f & 511;
        int col = w >> 5, rem = w & 31;
        int n0c = sec / 14, r = sec % 14;
        int s = r >> 1, b01 = r & 1;
        int n = n0c * 32 + b01 * 16 + col, k = s * 32 + rem;
        u16 v = 0;
        if (n < 300) {
            if (k < 100) v = f2bf(l1w1[k * 300 + n] - l1w1[(100 + k) * 300 + n]);
            else if (k >= 112 && k < 212) v = f2bf(l1w1[(100 + (k - 112)) * 300 + n]);
        }
        wt1[f] = v; return;
    }
    f -= 71680;
    if (f < 204800) {                      // wt2a / wt2b: 300x300, K=320 (KA=10)
        const float* src = (f < 102400) ? l0w2 : l1w2;
        u16* dst = (f < 102400) ? wt2a : wt2b;
        int f2 = (f < 102400) ? f : f - 102400;
        int sec = f2 >> 9, w = f2 & 511;
        int col = w >> 5, rem = w & 31;
        int n0c = sec / 20, r = sec % 20;
        int s = r >> 1, b01 = r & 1;
        int n = n0c * 32 + b01 * 16 + col, k = s * 32 + rem;
        dst[f2] = (n < 300 && k < 300) ? f2bf(src[k * 300 + n]) : (u16)0;
        return;
    }
    f -= 204800;
    if (f < 71680) {                       // wt3a / wt3b: 300x100 -> [112 n3][320 k]
        const float* src = (f < 35840) ? l0w3 : l1w3;
        u16* dst = (f < 35840) ? wt3a : wt3b;
        int f2 = (f < 35840) ? f : f - 35840;
        int sec = f2 >> 9, w = f2 & 511;
        int col = w >> 5, rem = w & 31;
        int ch = sec / 7, u = sec % 7;
        int n3 = u * 16 + col, k = ch * 32 + rem;
        dst[f2] = (n3 < 100 && k < 300) ? f2bf(src[k * 100 + n3]) : (u16)0;
        return;
    }
}

// ---------------------------------------------------------------------------
// edge_mlp: fused per-edge 3-layer MLP + clamped scatter-max via MFMA.
// R11: ONE WAVE = 32 EDGES (two 16-row A-tiles). Every weight fragment now
// feeds 2 MFMA -> L2 weight traffic halves (10.5 -> 5.3 GB/dispatch) and
// per-wave MFMA:load ratio doubles (54:27 per chunk). GEMM1 output transits
// chunk-by-chunk through a tiny wave-private LDS buffer (2.5 KB/wave)
// directly into persistent a2 fragments - the 42 KB H1 buffer is gone.
// No barriers anywhere (wave-private LDS; lgkmcnt ordering).
// Layouts (m89/m120): A: m=lane&15,k=quad*8+j ; B: n=lane&15,k=quad*8+j ;
// C/D: col=lane&15, row=quad*4+reg.
// relu(where(cnt>0,segmax,0)) == int atomicMax of relu'd msgs into 0-init buf.
// ---------------------------------------------------------------------------
template<bool FIRST>
__global__ __launch_bounds__(256, 1)
void edge_mlp(const float* __restrict__ X, const float* __restrict__ H0,
              const int* __restrict__ ei,
              const u16* __restrict__ W1, const float* __restrict__ B1,
              const u16* __restrict__ W2, const float* __restrict__ B2,
              const u16* __restrict__ W3, const float* __restrict__ B3,
              float* __restrict__ agg)
{
    constexpr int KP = FIRST ? 32 : 224;
    constexpr int KA = KP / 32;
    __shared__ __align__(16) u16 SCR[4 * 32 * 40];    // 10,240 B (wave-private slices)

    const int tid  = threadIdx.x;
    const int wave = tid >> 6, lane = tid & 63;
    const int col  = lane & 15, kq = lane >> 4;
    const int ebase = blockIdx.x * 128 + wave * 32;   // 32 edges per wave
    const int fragoff = col * 32 + kq * 8;            // in-section lane offset

    u16* SCw = SCR + wave * (32 * 40);

    s16x8 aF[2][KA];
    if constexpr (FIRST) {
        // gather [xi | xj] for 32 edges into SCw as bf16 IN[32][40] (K pad 32)
        for (int s = lane; s < 32 * 32; s += 64) {
            int e = s >> 5, k = s & 31;
            u16 v = 0;
            if (k < 7)                  v = f2bf(X[(size_t)ei[E_ + ebase + e] * 7 + k]);
            else if (k >= 16 && k < 23) v = f2bf(X[(size_t)ei[ebase + e] * 7 + (k - 16)]);
            SCw[e * 40 + k] = v;
        }
        #pragma unroll
        for (int rt = 0; rt < 2; ++rt)
            aF[rt][0] = ldv(SCw + (rt * 16 + col) * 40 + kq * 8);
    } else {
        // build A-fragments from global agg0 (h0, f32 -> bf16), 2 row-tiles
        #pragma unroll
        for (int rt = 0; rt < 2; ++rt) {
            const int dn = ei[E_ + ebase + rt * 16 + col];   // x_i
            const int sn = ei[ebase + rt * 16 + col];        // x_j
            #pragma unroll
            for (int s = 0; s < KA; ++s) {
                int b = s * 4 + kq;                // 8-elem k-group, 0..27; k = 8b+j
                int node = (b < 14) ? dn : sn;
                int c = ((b < 14) ? b : b - 14) * 8;
                s16x8 t = {0, 0, 0, 0, 0, 0, 0, 0};
                if (c < 104) {
                    const float* r = H0 + (size_t)node * 100 + c;
                    float4 lo = *(const float4*)r;
                    t[0] = (short)f2bf(lo.x); t[1] = (short)f2bf(lo.y);
                    t[2] = (short)f2bf(lo.z); t[3] = (short)f2bf(lo.w);
                    if (c < 96) {
                        float4 hi = *(const float4*)(r + 4);
                        t[4] = (short)f2bf(hi.x); t[5] = (short)f2bf(hi.y);
                        t[6] = (short)f2bf(hi.z); t[7] = (short)f2bf(hi.w);
                    }
                }
                aF[rt][s] = t;
            }
        }
    }

    // GEMM1: [32,KP] x Wt1 -> per-chunk H1 transit -> persistent a2 fragments
    s16x8 a2[2][10];
    #pragma unroll 1
    for (int t2 = 0; t2 < 10; ++t2) {
        const int n0 = t2 * 32;
        const u16* w0 = W1 + (size_t)(t2 * 2 * KA) * 512 + fragoff;
        f32x4 z = {0.f, 0.f, 0.f, 0.f};
        f32x4 ac[2][2] = {{z, z}, {z, z}};
        #pragma unroll
        for (int s = 0; s < KA; ++s) {
            s16x8 b0 = ldv(w0 + (2 * s) * 512);       // contiguous 1 KB wave-load
            s16x8 b1 = ldv(w0 + (2 * s + 1) * 512);
            #pragma unroll
            for (int rt = 0; rt < 2; ++rt) {
                ac[rt][0] = MFMA(aF[rt][s], b0, ac[rt][0]);
                ac[rt][1] = MFMA(aF[rt][s], b1, ac[rt][1]);
            }
        }
        const int n = n0 + col;
        const float bi0 = (n < 300)      ? B1[n]      : 0.f;
        const float bi1 = (n + 16 < 300) ? B1[n + 16] : 0.f;
        #pragma unroll
        for (int rt = 0; rt < 2; ++rt)
            #pragma unroll
            for (int r = 0; r < 4; ++r) {
                int row = rt * 16 + kq * 4 + r;
                SCw[row * 40 + col]      = f2bf(fmaxf(ac[rt][0][r] + bi0, 0.f));
                SCw[row * 40 + col + 16] = f2bf(fmaxf(ac[rt][1][r] + bi1, 0.f));
            }
        // wave-private: lgkmcnt write->read ordering; chunk t2 of H1 == a2[.][t2]
        #pragma unroll
        for (int rt = 0; rt < 2; ++rt)
            a2[rt][t2] = ldv(SCw + (rt * 16 + col) * 40 + kq * 8);
    }

    f32x4 mac[2][7];
    #pragma unroll
    for (int rt = 0; rt < 2; ++rt)
        #pragma unroll
        for (int u = 0; u < 7; ++u) { f32x4 z = {0.f, 0.f, 0.f, 0.f}; mac[rt][u] = z; }

    // GEMM2 (K=320) fused with GEMM3 in 32-wide chunks of H2
    #pragma unroll 1
    for (int ch = 0; ch < 10; ++ch) {
        const int n0 = ch * 32;
        const u16* w0 = W2 + (size_t)(ch * 20) * 512 + fragoff;
        f32x4 z = {0.f, 0.f, 0.f, 0.f};
        f32x4 ac[2][2] = {{z, z}, {z, z}};
        #pragma unroll
        for (int s = 0; s < 10; ++s) {
            s16x8 b0 = ldv(w0 + (2 * s) * 512);       // contiguous 1 KB wave-load
            s16x8 b1 = ldv(w0 + (2 * s + 1) * 512);
            #pragma unroll
            for (int rt = 0; rt < 2; ++rt) {
                ac[rt][0] = MFMA(a2[rt][s], b0, ac[rt][0]);
                ac[rt][1] = MFMA(a2[rt][s], b1, ac[rt][1]);
            }
        }
        const int n = n0 + col;
        const float bi0 = (n < 300)      ? B2[n]      : 0.f;
        const float bi1 = (n + 16 < 300) ? B2[n + 16] : 0.f;
        #pragma unroll
        for (int rt = 0; rt < 2; ++rt)
            #pragma unroll
            for (int r = 0; r < 4; ++r) {
                int row = rt * 16 + kq * 4 + r;
                SCw[row * 40 + col]      = f2bf(fmaxf(ac[rt][0][r] + bi0, 0.f));
                SCw[row * 40 + col + 16] = f2bf(fmaxf(ac[rt][1][r] + bi1, 0.f));
            }
        // wave-private SCw: lgkmcnt ordering only, no barrier
        s16x8 a3_0 = ldv(SCw + col * 40 + kq * 8);
        s16x8 a3_1 = ldv(SCw + (16 + col) * 40 + kq * 8);
        #pragma unroll
        for (int u = 0; u < 7; ++u) {
            s16x8 b3 = ldv(W3 + (size_t)(ch * 7 + u) * 512 + fragoff);  // 1 KB
            mac[0][u] = MFMA(a3_0, b3, mac[0][u]);
            mac[1][u] = MFMA(a3_1, b3, mac[1][u]);
        }
    }

    // scatter-max: per (rt,u,r) instruction lanes cover 16 consecutive
    // channels x 4 edges -> coalesced atomic sectors. Msgs clamped >=0.
    #pragma unroll
    for (int rt = 0; rt < 2; ++rt) {
        const int e0 = ebase + rt * 16 + kq * 4;
        int dsts[4];
        #pragma unroll
        for (int r = 0; r < 4; ++r) dsts[r] = ei[E_ + e0 + r];
        #pragma unroll
        for (int u = 0; u < 7; ++u) {
            int c3 = u * 16 + col;
            if (c3 < 100) {
                float bi = B3[c3];
                #pragma unroll
                for (int r = 0; r < 4; ++r) {
                    float v = fmaxf(mac[rt][u][r] + bi, 0.f);
                    atomicMax((int*)(agg + (size_t)dsts[r] * 100 + c3), __float_as_int(v));
                }
            }
        }
    }
}

// ---------------------------------------------------------------------------
// pool: one block per graph (batch sorted -> binary-search bounds).
// pooled[g] = [addp(100) | meanp(100) | maxp(100) | u(2)]
// ---------------------------------------------------------------------------
__global__ __launch_bounds__(256)
void pool(const float* __restrict__ agg1, const int* __restrict__ batch,
          const float* __restrict__ u, float* __restrict__ pooled)
{
    const int g = blockIdx.x;
    int lo = 0, hi = N_;
    while (lo < hi) { int mid = (lo + hi) >> 1; if (batch[mid] < g) lo = mid + 1; else hi = mid; }
    const int start = lo;
    int lo2 = start, hi2 = N_;
    while (lo2 < hi2) { int mid = (lo2 + hi2) >> 1; if (batch[mid] < g + 1) lo2 = mid + 1; else hi2 = mid; }
    const int end = lo2;

    const int c = threadIdx.x & 127, half = threadIdx.x >> 7;
    float sm = 0.f, mx = 0.f;
    if (c < 100)
        for (int n = start + half; n < end; n += 2) {
            float v = agg1[(size_t)n * 100 + c];
            sm += v; mx = fmaxf(mx, v);
        }
    __shared__ float ssum[128], smax[128];
    if (half) { ssum[c] = sm; smax[c] = mx; }
    __syncthreads();
    if (!half && c < 100) {
        sm += ssum[c]; mx = fmaxf(mx, smax[c]);
        int cnt = end - start;
        pooled[g * 302 + c]       = sm;
        pooled[g * 302 + 100 + c] = sm / fmaxf((float)cnt, 1.f);
        pooled[g * 302 + 200 + c] = mx;   // h>=0 so zero-init max == where(cnt>0,.)
    }
    if (threadIdx.x == 0) {
        pooled[g * 302 + 300] = u[g * 2];
        pooled[g * 302 + 301] = u[g * 2 + 1];
    }
}

// ---------------------------------------------------------------------------
// final 302 -> 100 -> 100 -> 2 MLP, one block per graph, fp32
// ---------------------------------------------------------------------------
__global__ __launch_bounds__(128)
void final_mlp(const float* __restrict__ pooled,
               const float* __restrict__ w1, const float* __restrict__ b1,
               const float* __restrict__ w2, const float* __restrict__ b2,
               const float* __restrict__ w3, const float* __restrict__ b3,
               float* __restrict__ out)
{
    const int g = blockIdx.x, t = threadIdx.x;
    __shared__ float P[302], T1[100], T2[100];
    for (int i = t; i < 302; i += 128) P[i] = pooled[g * 302 + i];
    __syncthreads();
    if (t < 100) {
        float a = b1[t];
        for (int i = 0; i < 302; ++i) a = fmaf(P[i], w1[i * 100 + t], a);
        T1[t] = fmaxf(a, 0.f);
    }
    __syncthreads();
    if (t < 100) {
        float a = b2[t];
        for (int i = 0; i < 100; ++i) a = fmaf(T1[i], w2[i * 100 + t], a);
        T2[t] = fmaxf(a, 0.f);
    }
    __syncthreads();
    if (t < 2) {
        float a = b3[t];
        for (int i = 0; i < 100; ++i) a = fmaf(T2[i], w3[i * 2 + t], a);
        out[g * 2 + t] = a;
    }
}

// ---------------------------------------------------------------------------
extern "C" void kernel_launch(void* const* d_in, const int* in_sizes, int n_in,
                              void* d_out, int out_size, void* d_ws, size_t ws_size,
                              hipStream_t stream)
{
    const float* x     = (const float*)d_in[0];
    const int*   ei    = (const int*)d_in[1];
    const int*   batch = (const int*)d_in[2];
    const float* uu    = (const float*)d_in[3];
    const float *l0w1 = (const float*)d_in[4],  *l0b1 = (const float*)d_in[5];
    const float *l0w2 = (const float*)d_in[6],  *l0b2 = (const float*)d_in[7];
    const float *l0w3 = (const float*)d_in[8],  *l0b3 = (const float*)d_in[9];
    const float *l1w1 = (const float*)d_in[10], *l1b1 = (const float*)d_in[11];
    const float *l1w2 = (const float*)d_in[12], *l1b2 = (const float*)d_in[13];
    const float *l1w3 = (const float*)d_in[14], *l1b3 = (const float*)d_in[15];
    const float *lw1  = (const float*)d_in[16], *lb1  = (const float*)d_in[17];
    const float *lw2  = (const float*)d_in[18], *lb2  = (const float*)d_in[19];
    const float *lw3  = (const float*)d_in[20], *lb3  = (const float*)d_in[21];

    char* w = (char*)d_ws;
    float* agg0   = (float*)(w);                    // 20,000,000 B
    float* agg1   = (float*)(w + 20000000);         // 20,000,000 B
    float* pooled = (float*)(w + 40000000);         //     77,312 B
    u16* wt0  = (u16*)(w + 40077312);               //     20,480 B
    u16* wt1  = (u16*)(w + 40097792);               //    143,360 B
    u16* wt2a = (u16*)(w + 40241152);               //    204,800 B
    u16* wt2b = (u16*)(w + 40445952);               //    204,800 B
    u16* wt3a = (u16*)(w + 40650752);               //     71,680 B
    u16* wt3b = (u16*)(w + 40722432);               //     71,680 B  (total ~38.9 MiB)

    ModelGNN_35304631174019_kernel<<<11166, 256, 0, stream>>>(
        l0w1, l0w2, l0w3, l1w1, l1w2, l1w3,
        (float4*)d_ws, wt0, wt1, wt2a, wt2b, wt3a, wt3b);
    edge_mlp<true ><<<3125, 256, 0, stream>>>(x, nullptr, ei, wt0, l0b1, wt2a, l0b2, wt3a, l0b3, agg0);
    edge_mlp<false><<<3125, 256, 0, stream>>>(nullptr, agg0, ei, wt1, l1b1, wt2b, l1b2, wt3b, l1b3, agg1);
    pool<<<G_, 256, 0, stream>>>(agg1, batch, uu, pooled);
    final_mlp<<<G_, 128, 0, stream>>>(pooled, lw1, lb1, lw2, lb2, lw3, lb3, (float*)d_out);
}